// Round 4
// baseline (81.195 us; speedup 1.0000x reference)
//
#include <hip/hip_runtime.h>
#include <hip/hip_bf16.h>

// SioConv: out[b,i,d] = Re(h[i]) where
//   a[b,l,d] = (re,im) * rsqrt(m2) * exp(-m2),  (re,im) = x[b,l,:] @ W_a rows 2d/2d+1
//   g[i] = a_i * (x_hat[i] + g[i+1])   (backward scan, g[L]=0)
//   out[i] = Re(g[i]) + Re(x_hat[i-1]) (i>=1), out[L-1] += x[b,L-1,d]
//   x_hat[0] = h0 (complex), x_hat[k] = x[b,k-1,d] (real)
//
// R3 analysis: old gemm was LDS-b128-throughput bound (3 ds_read_b128 per
// output, ~3.1 MB LDS reads/CU / 85 B/cyc = ~14us). R4: no inner-loop LDS.
//   pack_w: W -> Wp[k4][d][8] so W operand is a coalesced 32B/lane stream.
//   gemm:   wave = 4 l-rows (uniform x via readfirstlane) x 64 d-lanes,
//           4-way l register blocking: 32 FMA per 6 loads.
//   scan:   lanes = d (coalesced), 16-seg serial fold + LDS combine.

constexpr int B = 2, L = 256, D = 256, K = 256;

// Wp[((k4*D)+d)*8 + j*2 + c] = W[2d+c][k4*4+j]
__global__ __launch_bounds__(256) void pack_w_kernel(
    const float* __restrict__ W,   // [2D, K]
    float* __restrict__ Wp)        // [K/4 * D * 8]
{
    const int g  = blockIdx.x * 256 + threadIdx.x;  // 0..16383
    const int k4 = g >> 8;                          // 0..63
    const int d  = g & 255;
    const float4 r0 = *(const float4*)(W + (size_t)(2 * d) * K + 4 * k4);
    const float4 r1 = *(const float4*)(W + (size_t)(2 * d + 1) * K + 4 * k4);
    float4* dst = (float4*)(Wp + (size_t)(k4 * D + d) * 8);
    dst[0] = make_float4(r0.x, r1.x, r0.y, r1.y);   // lanes: 32B stride, coalesced
    dst[1] = make_float4(r0.z, r1.z, r0.w, r1.w);
}

// grid (D/64, L/8, B), 128 threads = 2 waves; wave w owns l = l0+4w..+3, lanes = d.
__global__ __launch_bounds__(128) void gemm_a_kernel(
    const float* __restrict__ x,    // [B, L, K]
    const float* __restrict__ Wp,   // packed
    float2* __restrict__ a)         // [B, L, D] (l-major)
{
    const int d    = blockIdx.x * 64 + (threadIdx.x & 63);
    const int wv   = __builtin_amdgcn_readfirstlane(threadIdx.x >> 6);
    const int b    = blockIdx.z;
    const int l0   = blockIdx.y * 8 + wv * 4;       // wave-uniform

    const float* xrow0 = x + (size_t)(b * L + l0) * K;       // uniform base
    const float* wp    = Wp + (size_t)d * 8;

    float accr[4] = {0.f, 0.f, 0.f, 0.f};
    float acci[4] = {0.f, 0.f, 0.f, 0.f};

#pragma unroll 4
    for (int k4 = 0; k4 < K / 4; ++k4) {
        const float4 wp0 = *(const float4*)(wp + (size_t)k4 * D * 8);
        const float4 wp1 = *(const float4*)(wp + (size_t)k4 * D * 8 + 4);
#pragma unroll
        for (int j = 0; j < 4; ++j) {
            // uniform (wave-scalar) x load
            const float4 xv = *(const float4*)(xrow0 + (size_t)j * K + k4 * 4);
            accr[j] += xv.x * wp0.x + xv.y * wp0.z + xv.z * wp1.x + xv.w * wp1.z;
            acci[j] += xv.x * wp0.y + xv.y * wp0.w + xv.z * wp1.y + xv.w * wp1.w;
        }
    }

#pragma unroll
    for (int j = 0; j < 4; ++j) {
        const float re = accr[j], im = acci[j];
        const float m2 = re * re + im * im;
        const float s  = rsqrtf(m2) * expf(-m2);
        a[(size_t)(b * L + l0 + j) * D + d] = make_float2(re * s, im * s);  // coalesced
    }
}

// grid (B * D/64) = 8 blocks, 1024 threads = 16 waves.
// thread: lane -> d, seg (tid>>6) -> l in [seg*16, seg*16+16).
__global__ __launch_bounds__(1024) void scan_h_kernel(
    const float* __restrict__ x,    // [B, L, D]
    const float2* __restrict__ a,   // [B, L, D]
    const float* __restrict__ h0r,  // [D]
    const float* __restrict__ h0i,  // [D]
    float* __restrict__ out)        // [B, L, D]
{
    const int b    = blockIdx.x >> 2;
    const int d    = (blockIdx.x & 3) * 64 + (threadIdx.x & 63);
    const int seg  = threadIdx.x >> 6;     // 0..15
    const int l0   = seg * 16;
    const size_t base = (size_t)b * L * D + d;

    // Pass 1 (ascending): segment map M = f_{l0} o f_{l0+1} o ... o f_{l0+15}
    //   compose M <- M o f_l : A <- A*a_l ; B <- B + A*(a_l*xhat_l)
    float Ar, Ai, Br, Bi;
    {
        const float2 al = a[base + (size_t)l0 * D];
        float xr, xi;
        if (l0 == 0) { xr = h0r[d]; xi = h0i[d]; }
        else         { xr = x[base + (size_t)(l0 - 1) * D]; xi = 0.f; }
        Ar = al.x; Ai = al.y;
        Br = al.x * xr - al.y * xi;
        Bi = al.x * xi + al.y * xr;
    }
#pragma unroll
    for (int l = l0 + 1; l < l0 + 16; ++l) {
        const float2 al = a[base + (size_t)l * D];
        const float xr  = x[base + (size_t)(l - 1) * D];   // real
        const float br = al.x * xr, bi = al.y * xr;
        const float nAr = Ar * al.x - Ai * al.y;
        const float nAi = Ar * al.y + Ai * al.x;
        Br += Ar * br - Ai * bi;
        Bi += Ar * bi + Ai * br;
        Ar = nAr; Ai = nAi;
    }

    __shared__ float4 Ms[16][64];          // 16 KB
    Ms[seg][threadIdx.x & 63] = make_float4(Ar, Ai, Br, Bi);
    __syncthreads();

    // Tail: G = (M_{seg+1} o ... o M_15)(0)  -- T starts as identity
    float Tr = 1.f, Ti = 0.f, Gr = 0.f, Gi = 0.f;
    for (int s = seg + 1; s < 16; ++s) {
        const float4 m = Ms[s][threadIdx.x & 63];
        Gr += Tr * m.z - Ti * m.w;
        Gi += Tr * m.w + Ti * m.z;
        const float nTr = Tr * m.x - Ti * m.y;
        const float nTi = Tr * m.y + Ti * m.x;
        Tr = nTr; Ti = nTi;
    }

    // Pass 2 (descending): g_l = a_l * (xhat_l + g_{l+1}), seeded with G.
    float gr = Gr, gi = Gi;
#pragma unroll
    for (int l = l0 + 15; l >= l0; --l) {
        const float2 al = a[base + (size_t)l * D];
        float xr, xi;
        if (l == 0) { xr = h0r[d]; xi = h0i[d]; }
        else        { xr = x[base + (size_t)(l - 1) * D]; xi = 0.f; }
        const float tr = xr + gr;
        const float ti = xi + gi;
        gr = al.x * tr - al.y * ti;
        gi = al.x * ti + al.y * tr;

        float o = gr;
        if (l >= 2)      o += x[base + (size_t)(l - 2) * D];
        else if (l == 1) o += h0r[d];
        if (l == L - 1)  o += x[base + (size_t)(L - 1) * D];
        out[base + (size_t)l * D] = o;     // coalesced
    }
}

extern "C" void kernel_launch(void* const* d_in, const int* in_sizes, int n_in,
                              void* d_out, int out_size, void* d_ws, size_t ws_size,
                              hipStream_t stream) {
    const float* x    = (const float*)d_in[0];   // B*L*D
    const float* W_a  = (const float*)d_in[1];   // 2D*D
    const float* h0r  = (const float*)d_in[2];   // D
    const float* h0i  = (const float*)d_in[3];   // D
    float* out = (float*)d_out;
    float*  Wp = (float*)d_ws;                          // 512 KB
    float2* a  = (float2*)((char*)d_ws + (size_t)(K / 4) * D * 8 * 4);  // 1 MB

    pack_w_kernel<<<dim3(64), dim3(256), 0, stream>>>(W_a, Wp);
    gemm_a_kernel<<<dim3(D / 64, L / 8, B), dim3(128), 0, stream>>>(x, Wp, a);
    scan_h_kernel<<<dim3(B * (D / 64)), dim3(1024), 0, stream>>>(x, a, h0r, h0i, out);
}